// Round 6
// baseline (802.183 us; speedup 1.0000x reference)
//
#include <hip/hip_runtime.h>
#include <hip/hip_bf16.h>
#include <math.h>
#include <stdint.h>

#define HH 768
#define TT 32
#define KK 832           // H + 2T
#define SS 2048
#define NSTEP 26         // KK / 32
#define NTOK 65536       // B*S
#define BM 32            // rows per block

typedef __attribute__((ext_vector_type(4))) float f32x4;
typedef __attribute__((ext_vector_type(8))) short bf16x8;
typedef __attribute__((ext_vector_type(4))) short bf16x4;

__device__ __forceinline__ short f2bf(float f) {
  union { float f; uint32_t u; } v; v.f = f;
  uint32_t u = v.u;
  return (short)((u + 0x7FFFu + ((u >> 16) & 1u)) >> 16);
}

// ---------------- transpose lin_W -> Btw[n][k] bf16 ----------------
__global__ void transpose_w_kernel(const float* __restrict__ lin_W,
                                   short* __restrict__ bt) {
  int i = blockIdx.x * 256 + threadIdx.x;
  if (i >= HH * KK) return;
  int n = i / KK;
  int k = i - n * KK;
  bt[i] = f2bf(lin_W[(size_t)k * HH + n]);
}

// ------------- gather kernel: build A[65536][832] bf16 -------------
__global__ __launch_bounds__(256) void gather_a_kernel(
    const int* __restrict__ input_ids, const float* __restrict__ ts,
    const float* __restrict__ ages, const float* __restrict__ W_word,
    const float* __restrict__ time_w, const float* __restrict__ time_phi,
    const float* __restrict__ age_w, const float* __restrict__ age_phi,
    short* __restrict__ Aws) {
  const int wave = threadIdx.x >> 6, lane = threadIdx.x & 63;
  const int t = blockIdx.x * 4 + wave;
  if (t >= NTOK) return;
  const float* wrow = W_word + (size_t)input_ids[t] * HH;
  const int s = t & (SS - 1);
  const float dt = (s == 0) ? 0.f : (ts[t] - ts[t - 1]);
  const float age = ages[t];
  short* dst = Aws + (size_t)t * KK;
#pragma unroll
  for (int c2 = 0; c2 < 2; ++c2) {
    int chunk = c2 * 64 + lane;
    if (chunk < 104) {
      int k = chunk * 8;
      bf16x8 v;
      if (k < HH) {
        f32x4 x0 = *(const f32x4*)(wrow + k);
        f32x4 x1 = *(const f32x4*)(wrow + k + 4);
        v[0] = f2bf(x0[0]); v[1] = f2bf(x0[1]); v[2] = f2bf(x0[2]); v[3] = f2bf(x0[3]);
        v[4] = f2bf(x1[0]); v[5] = f2bf(x1[1]); v[6] = f2bf(x1[2]); v[7] = f2bf(x1[3]);
      } else if (k < HH + TT) {
        int j = k - HH;
#pragma unroll
        for (int i = 0; i < 8; ++i)
          v[i] = f2bf(sinf(dt * time_w[j + i] + time_phi[j + i]));
      } else {
        int j = k - HH - TT;
#pragma unroll
        for (int i = 0; i < 8; ++i)
          v[i] = f2bf(sinf(age * age_w[j + i] + age_phi[j + i]));
      }
      *(bf16x8*)(dst + k) = v;
    }
  }
}

// ---------------- main GEMM + epilogue kernel (BM=32) ---------------
// NO LDS in the K-loop: B (1.2MB) is L2-resident, so each wave loads its
// MFMA fragments directly global->register (16B/lane dwordx4), zero
// barriers, compiler pipelines with counted vmcnt. LDS only for epilogue.
__global__ __launch_bounds__(512) void ehr_gemm_kernel(
    const int* __restrict__ type_ids, const int* __restrict__ visit_orders,
    const int* __restrict__ visit_segments, const float* __restrict__ W_type,
    const float* __restrict__ W_order, const float* __restrict__ W_seg,
    const float* __restrict__ lin_b, const float* __restrict__ ln_g,
    const float* __restrict__ ln_beta, const short* __restrict__ Aws,
    const short* __restrict__ Btw, float* __restrict__ out) {
  __shared__ float Os[16 * HH];   // 48KB epilogue store-staging
  __shared__ int tyl[BM], orl[BM], sgl[BM];
  __shared__ float redS[4][BM], redQ[4][BM];

  const int tid = threadIdx.x;
  const int t0 = blockIdx.x * BM;
  if (tid < BM) {
    tyl[tid] = type_ids[t0 + tid];
    orl[tid] = visit_orders[t0 + tid];
    sgl[tid] = visit_segments[t0 + tid];
  }
  const int lane = tid & 63, wave = tid >> 6;
  const int wm = wave >> 2, wn = wave & 3;   // wm in {0,1}, wn in {0..3}
  const int l15 = lane & 15, l4 = lane >> 4;

  // Fragment pointers (per-lane). A: row t0+wm*16+l15, k-chunk l4*8.
  // B fragment nf: row n = wn*192 + nf*16 + l15, same k-chunk.
  const short* aptr = Aws + (size_t)(t0 + wm * 16 + l15) * KK + l4 * 8;
  const short* bptr = Btw + (size_t)(wn * 192 + l15) * KK + l4 * 8;

  f32x4 acc[12];
#pragma unroll
  for (int nf = 0; nf < 12; ++nf) acc[nf] = (f32x4)(0.0f);

#pragma unroll 2
  for (int st = 0; st < NSTEP; ++st) {
    const int ko = st * 32;
    bf16x8 a = *(const bf16x8*)(aptr + ko);
#pragma unroll
    for (int nf = 0; nf < 12; ++nf) {
      bf16x8 b = *(const bf16x8*)(bptr + (size_t)nf * (16 * KK) + ko);
      acc[nf] = __builtin_amdgcn_mfma_f32_16x16x32_bf16(a, b, acc[nf], 0, 0, 0);
    }
  }

  __syncthreads();  // tyl/orl/sgl visibility for the epilogue

  // ---- epilogue: tanh + embedding adds + LayerNorm stats
  float sp[4], sq[4];
#pragma unroll
  for (int r = 0; r < 4; ++r) { sp[r] = 0.f; sq[r] = 0.f; }

#pragma unroll
  for (int nf = 0; nf < 12; ++nf) {
    int n = wn * 192 + nf * 16 + l15;
    float bias = lin_b[n];
#pragma unroll
    for (int r = 0; r < 4; ++r) {
      int row = wm * 16 + l4 * 4 + r;
      float z = tanhf(acc[nf][r] + bias);
      z += W_type[(size_t)tyl[row] * HH + n];
      z += W_order[(size_t)orl[row] * HH + n];
      z += W_seg[(size_t)sgl[row] * HH + n];
      acc[nf][r] = z;
      sp[r] += z;
      sq[r] += z * z;
    }
  }
#pragma unroll
  for (int m = 1; m < 16; m <<= 1) {
#pragma unroll
    for (int r = 0; r < 4; ++r) {
      sp[r] += __shfl_xor(sp[r], m, 64);
      sq[r] += __shfl_xor(sq[r], m, 64);
    }
  }
  if (l15 == 0) {
#pragma unroll
    for (int r = 0; r < 4; ++r) {
      int row = wm * 16 + l4 * 4 + r;
      redS[wn][row] = sp[r];
      redQ[wn][row] = sq[r];
    }
  }
  __syncthreads();

  float mu[4], rs[4];
#pragma unroll
  for (int r = 0; r < 4; ++r) {
    int row = wm * 16 + l4 * 4 + r;
    float s = redS[0][row] + redS[1][row] + redS[2][row] + redS[3][row];
    float q = redQ[0][row] + redQ[1][row] + redQ[2][row] + redQ[3][row];
    float m_ = s * (1.0f / 768.0f);
    float v_ = q * (1.0f / 768.0f) - m_ * m_;
    if (v_ < 0.f) v_ = 0.f;
    mu[r] = m_;
    rs[r] = rsqrtf(v_ + 1e-12f);
  }

  // ---- staged stores: 2 groups of 16 rows through LDS, contiguous out.
  // Fully unrolled; all acc indices compile-time (rule #20).
#pragma unroll
  for (int g = 0; g < 2; ++g) {
    __syncthreads();
    if (wm == g) {
#pragma unroll
      for (int nf = 0; nf < 12; ++nf) {
        int n = wn * 192 + nf * 16 + l15;
        float gg = ln_g[n], be = ln_beta[n];
#pragma unroll
        for (int r = 0; r < 4; ++r) {
          int lr = l4 * 4 + r;
          Os[lr * HH + n] = (acc[nf][r] - mu[r]) * rs[r] * gg + be;
        }
      }
    }
    __syncthreads();
    float* ob = out + (size_t)(t0 + g * 16) * HH;
#pragma unroll
    for (int q = 0; q < 6; ++q) {
      int idx4 = q * 512 + tid;
      ((f32x4*)ob)[idx4] = ((const f32x4*)Os)[idx4];
    }
  }
}

// =================== fallback (R1 kernel, ws-light) ===================
template <bool WS>
__global__ __launch_bounds__(512, 1) void ehr_fallback(
    const int* __restrict__ input_ids, const int* __restrict__ type_ids,
    const float* __restrict__ time_stamps, const float* __restrict__ ages,
    const int* __restrict__ visit_orders, const int* __restrict__ visit_segments,
    const float* __restrict__ W_word, const float* __restrict__ W_type,
    const float* __restrict__ W_order, const float* __restrict__ W_seg,
    const float* __restrict__ time_w, const float* __restrict__ time_phi,
    const float* __restrict__ age_w, const float* __restrict__ age_phi,
    const float* __restrict__ lin_W, const float* __restrict__ lin_b,
    const float* __restrict__ ln_g, const float* __restrict__ ln_beta,
    const short* __restrict__ bt_ws, float* __restrict__ out) {
  __shared__ short Bt[HH * 32];
  __shared__ short Atile[64 * 32];
  __shared__ float dtl[64], agel[64];
  __shared__ int idl[64], tyl[64], orl[64], sgl[64];
  __shared__ float tpar[128];
  __shared__ float redS[4][64], redQ[4][64];

  const int tid = threadIdx.x;
  const int t0 = blockIdx.x * 64;

  if (tid < 128) {
    int j = tid & 31;
    float v;
    if (tid < 32) v = time_w[j];
    else if (tid < 64) v = time_phi[j];
    else if (tid < 96) v = age_w[j];
    else v = age_phi[j];
    tpar[tid] = v;
  }
  if (tid < 64) {
    int t = t0 + tid;
    int s = t & (SS - 1);
    float tsv = time_stamps[t];
    dtl[tid] = (s == 0) ? 0.f : (tsv - time_stamps[t - 1]);
    agel[tid] = ages[t];
    idl[tid] = input_ids[t];
    tyl[tid] = type_ids[t];
    orl[tid] = visit_orders[t];
    sgl[tid] = visit_segments[t];
  }
  __syncthreads();

  const int lane = tid & 63, wave = tid >> 6;
  const int wm = wave >> 2, wn = wave & 3;
  const int l15 = lane & 15, l4 = lane >> 4;
  const int arow = tid >> 3, ac = tid & 7;
  const int myid = idl[arow];
  const float mydt = dtl[arow];
  const float myage = agel[arow];
  const float* wrow = W_word + (size_t)myid * HH;

  f32x4 acc[2][12];
#pragma unroll
  for (int mf = 0; mf < 2; ++mf)
#pragma unroll
    for (int nf = 0; nf < 12; ++nf) acc[mf][nf] = (f32x4)(0.0f);

  for (int st = 0; st < NSTEP; ++st) {
    const int k0 = st * 32;
    {
      int kg = k0 + ac * 4;
      bf16x4 w4;
      if (kg < HH) {
        const f32x4 v = *(const f32x4*)(wrow + kg);
        w4[0] = f2bf(v[0]); w4[1] = f2bf(v[1]);
        w4[2] = f2bf(v[2]); w4[3] = f2bf(v[3]);
      } else {
        int isAge = (kg >= HH + TT);
        int j = kg - (isAge ? (HH + TT) : HH);
        float x = isAge ? myage : mydt;
        int wof = isAge ? 64 : 0;
#pragma unroll
        for (int i = 0; i < 4; ++i)
          w4[i] = f2bf(sinf(x * tpar[wof + j + i] + tpar[wof + 32 + j + i]));
      }
      *(bf16x4*)(Atile + tid * 4) = w4;
    }
    if (WS) {
#pragma unroll
      for (int p = 0; p < 6; ++p) {
        int chunk = p * 8 + wave;
        short* ldst = Bt + chunk * 512;
        int n = chunk * 16 + (lane >> 2);
        int q = lane & 3;
        const short* src = bt_ws + (size_t)n * KK + k0 + q * 8;
        __builtin_amdgcn_global_load_lds(
            (const __attribute__((address_space(1))) unsigned int*)src,
            (__attribute__((address_space(3))) unsigned int*)ldst, 16, 0, 0);
      }
    } else {
#pragma unroll
      for (int i6 = 0; i6 < 6; ++i6) {
        int c = i6 * 512 + tid;
        int n = c >> 2, q = c & 3;
        int kb = k0 + q * 8;
        bf16x8 w8;
#pragma unroll
        for (int j = 0; j < 8; ++j) w8[j] = f2bf(lin_W[(size_t)(kb + j) * HH + n]);
        *(bf16x8*)(Bt + n * 32 + q * 8) = w8;
      }
    }
    __syncthreads();

    const bf16x8* Af = (const bf16x8*)Atile;
    const bf16x8* Bf = (const bf16x8*)Bt;
    bf16x8 a0 = Af[(wm * 32 + l15) * 4 + l4];
    bf16x8 a1 = Af[(wm * 32 + 16 + l15) * 4 + l4];
#pragma unroll
    for (int nf = 0; nf < 12; ++nf) {
      int n = wn * 192 + nf * 16 + l15;
      bf16x8 b = Bf[n * 4 + l4];
      acc[0][nf] = __builtin_amdgcn_mfma_f32_16x16x32_bf16(a0, b, acc[0][nf], 0, 0, 0);
      acc[1][nf] = __builtin_amdgcn_mfma_f32_16x16x32_bf16(a1, b, acc[1][nf], 0, 0, 0);
    }
    __syncthreads();
  }

  float sp[2][4], sq[2][4];
#pragma unroll
  for (int mf = 0; mf < 2; ++mf)
#pragma unroll
    for (int r = 0; r < 4; ++r) { sp[mf][r] = 0.f; sq[mf][r] = 0.f; }

#pragma unroll
  for (int nf = 0; nf < 12; ++nf) {
    int n = wn * 192 + nf * 16 + l15;
    float bias = lin_b[n];
#pragma unroll
    for (int mf = 0; mf < 2; ++mf) {
#pragma unroll
      for (int r = 0; r < 4; ++r) {
        int row = wm * 32 + mf * 16 + l4 * 4 + r;
        float z = tanhf(acc[mf][nf][r] + bias);
        z += W_type[(size_t)tyl[row] * HH + n];
        z += W_order[(size_t)orl[row] * HH + n];
        z += W_seg[(size_t)sgl[row] * HH + n];
        acc[mf][nf][r] = z;
        sp[mf][r] += z;
        sq[mf][r] += z * z;
      }
    }
  }
#pragma unroll
  for (int m = 1; m < 16; m <<= 1) {
#pragma unroll
    for (int mf = 0; mf < 2; ++mf)
#pragma unroll
      for (int r = 0; r < 4; ++r) {
        sp[mf][r] += __shfl_xor(sp[mf][r], m, 64);
        sq[mf][r] += __shfl_xor(sq[mf][r], m, 64);
      }
  }
  if (l15 == 0) {
#pragma unroll
    for (int mf = 0; mf < 2; ++mf)
#pragma unroll
      for (int r = 0; r < 4; ++r) {
        int row = wm * 32 + mf * 16 + l4 * 4 + r;
        redS[wn][row] = sp[mf][r];
        redQ[wn][row] = sq[mf][r];
      }
  }
  __syncthreads();

  float mu[2][4], rs[2][4];
#pragma unroll
  for (int mf = 0; mf < 2; ++mf)
#pragma unroll
    for (int r = 0; r < 4; ++r) {
      int row = wm * 32 + mf * 16 + l4 * 4 + r;
      float s = redS[0][row] + redS[1][row] + redS[2][row] + redS[3][row];
      float q = redQ[0][row] + redQ[1][row] + redQ[2][row] + redQ[3][row];
      float m_ = s * (1.0f / 768.0f);
      float v_ = q * (1.0f / 768.0f) - m_ * m_;
      if (v_ < 0.f) v_ = 0.f;
      mu[mf][r] = m_;
      rs[mf][r] = rsqrtf(v_ + 1e-12f);
    }

#pragma unroll
  for (int nf = 0; nf < 12; ++nf) {
    int n = wn * 192 + nf * 16 + l15;
    float g = ln_g[n], be = ln_beta[n];
#pragma unroll
    for (int mf = 0; mf < 2; ++mf) {
#pragma unroll
      for (int r = 0; r < 4; ++r) {
        int row = wm * 32 + mf * 16 + l4 * 4 + r;
        out[(size_t)(t0 + row) * HH + n] =
            (acc[mf][nf][r] - mu[mf][r]) * rs[mf][r] * g + be;
      }
    }
  }
}

extern "C" void kernel_launch(void* const* d_in, const int* in_sizes, int n_in,
                              void* d_out, int out_size, void* d_ws, size_t ws_size,
                              hipStream_t stream) {
  const int* input_ids = (const int*)d_in[0];
  const int* type_ids = (const int*)d_in[1];
  const float* time_stamps = (const float*)d_in[2];
  const float* ages = (const float*)d_in[3];
  const int* visit_orders = (const int*)d_in[4];
  const int* visit_segments = (const int*)d_in[5];
  const float* W_word = (const float*)d_in[6];
  const float* W_type = (const float*)d_in[7];
  const float* W_order = (const float*)d_in[8];
  const float* W_seg = (const float*)d_in[9];
  const float* time_w = (const float*)d_in[10];
  const float* time_phi = (const float*)d_in[11];
  const float* age_w = (const float*)d_in[12];
  const float* age_phi = (const float*)d_in[13];
  const float* lin_W = (const float*)d_in[14];
  const float* lin_b = (const float*)d_in[15];
  const float* ln_g = (const float*)d_in[16];
  const float* ln_beta = (const float*)d_in[17];
  float* out = (float*)d_out;

  const size_t a_bytes = (size_t)NTOK * KK * sizeof(short);   // ~109 MB
  const size_t bt_bytes = (size_t)HH * KK * sizeof(short);    // ~1.2 MB

  if (d_ws != nullptr && ws_size >= a_bytes + bt_bytes) {
    short* Aws = (short*)d_ws;
    short* Btw = (short*)((char*)d_ws + a_bytes);
    transpose_w_kernel<<<dim3((HH * KK + 255) / 256), dim3(256), 0, stream>>>(lin_W, Btw);
    gather_a_kernel<<<dim3(NTOK / 4), dim3(256), 0, stream>>>(
        input_ids, time_stamps, ages, W_word, time_w, time_phi, age_w, age_phi, Aws);
    ehr_gemm_kernel<<<dim3(NTOK / BM), dim3(512), 0, stream>>>(
        type_ids, visit_orders, visit_segments, W_type, W_order, W_seg,
        lin_b, ln_g, ln_beta, (const short*)Aws, (const short*)Btw, out);
  } else if (d_ws != nullptr && ws_size >= bt_bytes) {
    short* bt = (short*)d_ws;
    transpose_w_kernel<<<dim3((HH * KK + 255) / 256), dim3(256), 0, stream>>>(lin_W, bt);
    ehr_fallback<true><<<dim3(1024), dim3(512), 0, stream>>>(
        input_ids, type_ids, time_stamps, ages, visit_orders, visit_segments,
        W_word, W_type, W_order, W_seg, time_w, time_phi, age_w, age_phi,
        lin_W, lin_b, ln_g, ln_beta, (const short*)bt, out);
  } else {
    ehr_fallback<false><<<dim3(1024), dim3(512), 0, stream>>>(
        input_ids, type_ids, time_stamps, ages, visit_orders, visit_segments,
        W_word, W_type, W_order, W_seg, time_w, time_phi, age_w, age_phi,
        lin_W, lin_b, ln_g, ln_beta, nullptr, out);
  }
}

// Round 7
// 623.704 us; speedup vs baseline: 1.2862x; 1.2862x over previous
//
#include <hip/hip_runtime.h>
#include <hip/hip_bf16.h>
#include <math.h>
#include <stdint.h>

#define HH 768
#define TT 32
#define KK 832           // H + 2T
#define SS 2048
#define NSTEP 26         // KK / 32
#define NTOK 65536       // B*S

typedef __attribute__((ext_vector_type(4))) float f32x4;
typedef __attribute__((ext_vector_type(8))) short bf16x8;
typedef __attribute__((ext_vector_type(4))) short bf16x4;

__device__ __forceinline__ short f2bf(float f) {
  union { float f; uint32_t u; } v; v.f = f;
  uint32_t u = v.u;
  return (short)((u + 0x7FFFu + ((u >> 16) & 1u)) >> 16);
}

// ---------------- transpose lin_W -> Btw[n][k] bf16 ----------------
__global__ void transpose_w_kernel(const float* __restrict__ lin_W,
                                   short* __restrict__ bt) {
  int i = blockIdx.x * 256 + threadIdx.x;
  if (i >= HH * KK) return;
  int n = i / KK;
  int k = i - n * KK;
  bt[i] = f2bf(lin_W[(size_t)k * HH + n]);
}

// ------------- gather kernel: build A[65536][832] bf16 -------------
__global__ __launch_bounds__(256) void gather_a_kernel(
    const int* __restrict__ input_ids, const float* __restrict__ ts,
    const float* __restrict__ ages, const float* __restrict__ W_word,
    const float* __restrict__ time_w, const float* __restrict__ time_phi,
    const float* __restrict__ age_w, const float* __restrict__ age_phi,
    short* __restrict__ Aws) {
  const int wave = threadIdx.x >> 6, lane = threadIdx.x & 63;
  const int t = blockIdx.x * 4 + wave;
  if (t >= NTOK) return;
  const float* wrow = W_word + (size_t)input_ids[t] * HH;
  const int s = t & (SS - 1);
  const float dt = (s == 0) ? 0.f : (ts[t] - ts[t - 1]);
  const float age = ages[t];
  short* dst = Aws + (size_t)t * KK;
#pragma unroll
  for (int c2 = 0; c2 < 2; ++c2) {
    int chunk = c2 * 64 + lane;
    if (chunk < 104) {
      int k = chunk * 8;
      bf16x8 v;
      if (k < HH) {
        f32x4 x0 = *(const f32x4*)(wrow + k);
        f32x4 x1 = *(const f32x4*)(wrow + k + 4);
        v[0] = f2bf(x0[0]); v[1] = f2bf(x0[1]); v[2] = f2bf(x0[2]); v[3] = f2bf(x0[3]);
        v[4] = f2bf(x1[0]); v[5] = f2bf(x1[1]); v[6] = f2bf(x1[2]); v[7] = f2bf(x1[3]);
      } else if (k < HH + TT) {
        int j = k - HH;
#pragma unroll
        for (int i = 0; i < 8; ++i)
          v[i] = f2bf(sinf(dt * time_w[j + i] + time_phi[j + i]));
      } else {
        int j = k - HH - TT;
#pragma unroll
        for (int i = 0; i < 8; ++i)
          v[i] = f2bf(sinf(age * age_w[j + i] + age_phi[j + i]));
      }
      *(bf16x8*)(dst + k) = v;
    }
  }
}

// ------------- partial-N GEMM: 256 rows x 32 cols per block ---------
// B-slice (32 cols x 832 K = 52KB) staged ONCE into LDS; K-loop is
// barrier-free: per wave 2 global A-loads + 2 ds_read_b128 + 4 MFMA.
// Writes pre-LN f32 to out; per-row partial sums atomically to S/Q.
__global__ __launch_bounds__(512, 4) void gemm_part_kernel(
    const int* __restrict__ type_ids, const int* __restrict__ visit_orders,
    const int* __restrict__ visit_segments, const float* __restrict__ W_type,
    const float* __restrict__ W_order, const float* __restrict__ W_seg,
    const float* __restrict__ lin_b, const short* __restrict__ Aws,
    const short* __restrict__ Btw, float* __restrict__ S,
    float* __restrict__ Q, float* __restrict__ out) {
  __shared__ short Bl[52 * 512];   // 52KB: chunk c = kc*2+half, [lane][8]
  __shared__ int tyl[256], orl[256], sgl[256];

  // XCD-chunked bijective swizzle: 6144 blocks = 8 XCD x 768.
  // XCD x processes m-panels [x*32, x*32+32), each panel's 24 n-blocks
  // consecutively -> A panel read from HBM once, L2-hits after.
  const int bid = blockIdx.x;
  const int j = bid >> 3;
  const int mb = (bid & 7) * 32 + j / 24;
  const int nb = j % 24;
  const int m0 = mb * 256, n0 = nb * 32;

  const int tid = threadIdx.x, lane = tid & 63, w = tid >> 6;
  const int l15 = lane & 15, l4 = lane >> 4;

  // ---- stage B slice once (52 x 1KB DMA chunks)
#pragma unroll
  for (int p = 0; p < 7; ++p) {
    int c = p * 8 + w;
    if (c < 52) {
      int kc = c >> 1, half = c & 1;
      const short* src = Btw + (size_t)(n0 + half * 16 + l15) * KK + kc * 32 + l4 * 8;
      __builtin_amdgcn_global_load_lds(
          (const __attribute__((address_space(1))) unsigned int*)src,
          (__attribute__((address_space(3))) unsigned int*)(Bl + c * 512),
          16, 0, 0);
    }
  }
  if (tid < 256) {
    tyl[tid] = type_ids[m0 + tid];
    orl[tid] = visit_orders[m0 + tid];
    sgl[tid] = visit_segments[m0 + tid];
  }
  __syncthreads();   // the ONLY barrier

  // ---- barrier-free K loop
  const short* aptr = Aws + (size_t)(m0 + w * 32 + l15) * KK + l4 * 8;
  f32x4 acc00 = (f32x4)(0.f), acc01 = (f32x4)(0.f);
  f32x4 acc10 = (f32x4)(0.f), acc11 = (f32x4)(0.f);
  const bf16x8* Bf = (const bf16x8*)Bl;

#pragma unroll 2
  for (int st = 0; st < NSTEP; ++st) {
    bf16x8 a0 = *(const bf16x8*)(aptr + st * 32);
    bf16x8 a1 = *(const bf16x8*)(aptr + 16 * KK + st * 32);
    bf16x8 b0 = Bf[(st * 2 + 0) * 64 + lane];
    bf16x8 b1 = Bf[(st * 2 + 1) * 64 + lane];
    acc00 = __builtin_amdgcn_mfma_f32_16x16x32_bf16(a0, b0, acc00, 0, 0, 0);
    acc01 = __builtin_amdgcn_mfma_f32_16x16x32_bf16(a0, b1, acc01, 0, 0, 0);
    acc10 = __builtin_amdgcn_mfma_f32_16x16x32_bf16(a1, b0, acc10, 0, 0, 0);
    acc11 = __builtin_amdgcn_mfma_f32_16x16x32_bf16(a1, b1, acc11, 0, 0, 0);
  }

  // ---- epilogue: tanh + bias + 3 gathers; store pre-LN f32; partial sums
  const int nA = n0 + l15, nB = n0 + 16 + l15;
  const float biasA = lin_b[nA], biasB = lin_b[nB];
  float sp[2][4], sq[2][4];
#pragma unroll
  for (int mf = 0; mf < 2; ++mf)
#pragma unroll
    for (int r = 0; r < 4; ++r) { sp[mf][r] = 0.f; sq[mf][r] = 0.f; }

#pragma unroll
  for (int mf = 0; mf < 2; ++mf) {
#pragma unroll
    for (int r = 0; r < 4; ++r) {
      int row_l = w * 32 + mf * 16 + l4 * 4 + r;
      size_t ty = (size_t)tyl[row_l] * HH;
      size_t od = (size_t)orl[row_l] * HH;
      size_t sg = (size_t)sgl[row_l] * HH;
      float zA = tanhf((mf ? acc10[r] : acc00[r]) + biasA)
                 + W_type[ty + nA] + W_order[od + nA] + W_seg[sg + nA];
      float zB = tanhf((mf ? acc11[r] : acc01[r]) + biasB)
                 + W_type[ty + nB] + W_order[od + nB] + W_seg[sg + nB];
      float* op = out + (size_t)(m0 + row_l) * HH;
      op[nA] = zA;
      op[nB] = zB;
      sp[mf][r] += zA + zB;
      sq[mf][r] += zA * zA + zB * zB;
    }
  }
#pragma unroll
  for (int m = 1; m < 16; m <<= 1) {
#pragma unroll
    for (int mf = 0; mf < 2; ++mf)
#pragma unroll
      for (int r = 0; r < 4; ++r) {
        sp[mf][r] += __shfl_xor(sp[mf][r], m, 64);
        sq[mf][r] += __shfl_xor(sq[mf][r], m, 64);
      }
  }
  if (l15 == 0) {
#pragma unroll
    for (int mf = 0; mf < 2; ++mf)
#pragma unroll
      for (int r = 0; r < 4; ++r) {
        int row_g = m0 + w * 32 + mf * 16 + l4 * 4 + r;
        atomicAdd(&S[row_g], sp[mf][r]);
        atomicAdd(&Q[row_g], sq[mf][r]);
      }
  }
}

// ------------- final LayerNorm pass: in-place on out ----------------
__global__ __launch_bounds__(256) void ln_final_kernel(
    const float* __restrict__ S, const float* __restrict__ Q,
    const float* __restrict__ ln_g, const float* __restrict__ ln_beta,
    float* __restrict__ out) {
  const int lane = threadIdx.x & 63, w = threadIdx.x >> 6;
  const int c0 = lane * 4;
  const f32x4 g0 = *(const f32x4*)(ln_g + c0);
  const f32x4 g1 = *(const f32x4*)(ln_g + 256 + c0);
  const f32x4 g2 = *(const f32x4*)(ln_g + 512 + c0);
  const f32x4 e0 = *(const f32x4*)(ln_beta + c0);
  const f32x4 e1 = *(const f32x4*)(ln_beta + 256 + c0);
  const f32x4 e2 = *(const f32x4*)(ln_beta + 512 + c0);
  const int wid = blockIdx.x * 4 + w;   // 0..8191
#pragma unroll 1
  for (int i = 0; i < 8; ++i) {
    int row = wid + i * 8192;
    float* rp = out + (size_t)row * HH;
    f32x4 x0 = *(const f32x4*)(rp + c0);
    f32x4 x1 = *(const f32x4*)(rp + 256 + c0);
    f32x4 x2 = *(const f32x4*)(rp + 512 + c0);
    float s = S[row], q = Q[row];
    float mu = s * (1.0f / 768.0f);
    float var = q * (1.0f / 768.0f) - mu * mu;
    if (var < 0.f) var = 0.f;
    float rs = rsqrtf(var + 1e-12f);
    f32x4 y0, y1, y2;
#pragma unroll
    for (int k = 0; k < 4; ++k) {
      y0[k] = (x0[k] - mu) * rs * g0[k] + e0[k];
      y1[k] = (x1[k] - mu) * rs * g1[k] + e1[k];
      y2[k] = (x2[k] - mu) * rs * g2[k] + e2[k];
    }
    *(f32x4*)(rp + c0) = y0;
    *(f32x4*)(rp + 256 + c0) = y1;
    *(f32x4*)(rp + 512 + c0) = y2;
  }
}

// =================== fallback (R1 kernel, ws-light) ===================
template <bool WS>
__global__ __launch_bounds__(512, 1) void ehr_fallback(
    const int* __restrict__ input_ids, const int* __restrict__ type_ids,
    const float* __restrict__ time_stamps, const float* __restrict__ ages,
    const int* __restrict__ visit_orders, const int* __restrict__ visit_segments,
    const float* __restrict__ W_word, const float* __restrict__ W_type,
    const float* __restrict__ W_order, const float* __restrict__ W_seg,
    const float* __restrict__ time_w, const float* __restrict__ time_phi,
    const float* __restrict__ age_w, const float* __restrict__ age_phi,
    const float* __restrict__ lin_W, const float* __restrict__ lin_b,
    const float* __restrict__ ln_g, const float* __restrict__ ln_beta,
    const short* __restrict__ bt_ws, float* __restrict__ out) {
  __shared__ short Bt[HH * 32];
  __shared__ short Atile[64 * 32];
  __shared__ float dtl[64], agel[64];
  __shared__ int idl[64], tyl[64], orl[64], sgl[64];
  __shared__ float tpar[128];
  __shared__ float redS[4][64], redQ[4][64];

  const int tid = threadIdx.x;
  const int t0 = blockIdx.x * 64;

  if (tid < 128) {
    int j = tid & 31;
    float v;
    if (tid < 32) v = time_w[j];
    else if (tid < 64) v = time_phi[j];
    else if (tid < 96) v = age_w[j];
    else v = age_phi[j];
    tpar[tid] = v;
  }
  if (tid < 64) {
    int t = t0 + tid;
    int s = t & (SS - 1);
    float tsv = time_stamps[t];
    dtl[tid] = (s == 0) ? 0.f : (tsv - time_stamps[t - 1]);
    agel[tid] = ages[t];
    idl[tid] = input_ids[t];
    tyl[tid] = type_ids[t];
    orl[tid] = visit_orders[t];
    sgl[tid] = visit_segments[t];
  }
  __syncthreads();

  const int lane = tid & 63, wave = tid >> 6;
  const int wm = wave >> 2, wn = wave & 3;
  const int l15 = lane & 15, l4 = lane >> 4;
  const int arow = tid >> 3, ac = tid & 7;
  const int myid = idl[arow];
  const float mydt = dtl[arow];
  const float myage = agel[arow];
  const float* wrow = W_word + (size_t)myid * HH;

  f32x4 acc[2][12];
#pragma unroll
  for (int mf = 0; mf < 2; ++mf)
#pragma unroll
    for (int nf = 0; nf < 12; ++nf) acc[mf][nf] = (f32x4)(0.0f);

  for (int st = 0; st < NSTEP; ++st) {
    const int k0 = st * 32;
    {
      int kg = k0 + ac * 4;
      bf16x4 w4;
      if (kg < HH) {
        const f32x4 v = *(const f32x4*)(wrow + kg);
        w4[0] = f2bf(v[0]); w4[1] = f2bf(v[1]);
        w4[2] = f2bf(v[2]); w4[3] = f2bf(v[3]);
      } else {
        int isAge = (kg >= HH + TT);
        int j = kg - (isAge ? (HH + TT) : HH);
        float x = isAge ? myage : mydt;
        int wof = isAge ? 64 : 0;
#pragma unroll
        for (int i = 0; i < 4; ++i)
          w4[i] = f2bf(sinf(x * tpar[wof + j + i] + tpar[wof + 32 + j + i]));
      }
      *(bf16x4*)(Atile + tid * 4) = w4;
    }
    if (WS) {
#pragma unroll
      for (int p = 0; p < 6; ++p) {
        int chunk = p * 8 + wave;
        short* ldst = Bt + chunk * 512;
        int n = chunk * 16 + (lane >> 2);
        int q = lane & 3;
        const short* src = bt_ws + (size_t)n * KK + k0 + q * 8;
        __builtin_amdgcn_global_load_lds(
            (const __attribute__((address_space(1))) unsigned int*)src,
            (__attribute__((address_space(3))) unsigned int*)ldst, 16, 0, 0);
      }
    } else {
#pragma unroll
      for (int i6 = 0; i6 < 6; ++i6) {
        int c = i6 * 512 + tid;
        int n = c >> 2, q = c & 3;
        int kb = k0 + q * 8;
        bf16x8 w8;
#pragma unroll
        for (int j = 0; j < 8; ++j) w8[j] = f2bf(lin_W[(size_t)(kb + j) * HH + n]);
        *(bf16x8*)(Bt + n * 32 + q * 8) = w8;
      }
    }
    __syncthreads();

    const bf16x8* Af = (const bf16x8*)Atile;
    const bf16x8* Bf = (const bf16x8*)Bt;
    bf16x8 a0 = Af[(wm * 32 + l15) * 4 + l4];
    bf16x8 a1 = Af[(wm * 32 + 16 + l15) * 4 + l4];
#pragma unroll
    for (int nf = 0; nf < 12; ++nf) {
      int n = wn * 192 + nf * 16 + l15;
      bf16x8 b = Bf[n * 4 + l4];
      acc[0][nf] = __builtin_amdgcn_mfma_f32_16x16x32_bf16(a0, b, acc[0][nf], 0, 0, 0);
      acc[1][nf] = __builtin_amdgcn_mfma_f32_16x16x32_bf16(a1, b, acc[1][nf], 0, 0, 0);
    }
    __syncthreads();
  }

  float sp[2][4], sq[2][4];
#pragma unroll
  for (int mf = 0; mf < 2; ++mf)
#pragma unroll
    for (int r = 0; r < 4; ++r) { sp[mf][r] = 0.f; sq[mf][r] = 0.f; }

#pragma unroll
  for (int nf = 0; nf < 12; ++nf) {
    int n = wn * 192 + nf * 16 + l15;
    float bias = lin_b[n];
#pragma unroll
    for (int mf = 0; mf < 2; ++mf) {
#pragma unroll
      for (int r = 0; r < 4; ++r) {
        int row = wm * 32 + mf * 16 + l4 * 4 + r;
        float z = tanhf(acc[mf][nf][r] + bias);
        z += W_type[(size_t)tyl[row] * HH + n];
        z += W_order[(size_t)orl[row] * HH + n];
        z += W_seg[(size_t)sgl[row] * HH + n];
        acc[mf][nf][r] = z;
        sp[mf][r] += z;
        sq[mf][r] += z * z;
      }
    }
  }
#pragma unroll
  for (int m = 1; m < 16; m <<= 1) {
#pragma unroll
    for (int mf = 0; mf < 2; ++mf)
#pragma unroll
      for (int r = 0; r < 4; ++r) {
        sp[mf][r] += __shfl_xor(sp[mf][r], m, 64);
        sq[mf][r] += __shfl_xor(sq[mf][r], m, 64);
      }
  }
  if (l15 == 0) {
#pragma unroll
    for (int mf = 0; mf < 2; ++mf)
#pragma unroll
      for (int r = 0; r < 4; ++r) {
        int row = wm * 32 + mf * 16 + l4 * 4 + r;
        redS[wn][row] = sp[mf][r];
        redQ[wn][row] = sq[mf][r];
      }
  }
  __syncthreads();

  float mu[2][4], rs[2][4];
#pragma unroll
  for (int mf = 0; mf < 2; ++mf)
#pragma unroll
    for (int r = 0; r < 4; ++r) {
      int row = wm * 32 + mf * 16 + l4 * 4 + r;
      float s = redS[0][row] + redS[1][row] + redS[2][row] + redS[3][row];
      float q = redQ[0][row] + redQ[1][row] + redQ[2][row] + redQ[3][row];
      float m_ = s * (1.0f / 768.0f);
      float v_ = q * (1.0f / 768.0f) - m_ * m_;
      if (v_ < 0.f) v_ = 0.f;
      mu[mf][r] = m_;
      rs[mf][r] = rsqrtf(v_ + 1e-12f);
    }

#pragma unroll
  for (int nf = 0; nf < 12; ++nf) {
    int n = wn * 192 + nf * 16 + l15;
    float g = ln_g[n], be = ln_beta[n];
#pragma unroll
    for (int mf = 0; mf < 2; ++mf) {
#pragma unroll
      for (int r = 0; r < 4; ++r) {
        int row = wm * 32 + mf * 16 + l4 * 4 + r;
        out[(size_t)(t0 + row) * HH + n] =
            (acc[mf][nf][r] - mu[mf][r]) * rs[mf][r] * g + be;
      }
    }
  }
}

extern "C" void kernel_launch(void* const* d_in, const int* in_sizes, int n_in,
                              void* d_out, int out_size, void* d_ws, size_t ws_size,
                              hipStream_t stream) {
  const int* input_ids = (const int*)d_in[0];
  const int* type_ids = (const int*)d_in[1];
  const float* time_stamps = (const float*)d_in[2];
  const float* ages = (const float*)d_in[3];
  const int* visit_orders = (const int*)d_in[4];
  const int* visit_segments = (const int*)d_in[5];
  const float* W_word = (const float*)d_in[6];
  const float* W_type = (const float*)d_in[7];
  const float* W_order = (const float*)d_in[8];
  const float* W_seg = (const float*)d_in[9];
  const float* time_w = (const float*)d_in[10];
  const float* time_phi = (const float*)d_in[11];
  const float* age_w = (const float*)d_in[12];
  const float* age_phi = (const float*)d_in[13];
  const float* lin_W = (const float*)d_in[14];
  const float* lin_b = (const float*)d_in[15];
  const float* ln_g = (const float*)d_in[16];
  const float* ln_beta = (const float*)d_in[17];
  float* out = (float*)d_out;

  const size_t a_bytes = (size_t)NTOK * KK * sizeof(short);   // ~109 MB
  const size_t bt_bytes = (size_t)HH * KK * sizeof(short);    // ~1.3 MB
  const size_t st_bytes = (size_t)NTOK * sizeof(float);       // 256 KB each

  if (d_ws != nullptr && ws_size >= a_bytes + bt_bytes + 2 * st_bytes) {
    short* Aws = (short*)d_ws;
    short* Btw = (short*)((char*)d_ws + a_bytes);
    float* S = (float*)((char*)d_ws + a_bytes + bt_bytes);
    float* Q = S + NTOK;
    hipMemsetAsync(S, 0, 2 * st_bytes, stream);
    transpose_w_kernel<<<dim3((HH * KK + 255) / 256), dim3(256), 0, stream>>>(lin_W, Btw);
    gather_a_kernel<<<dim3(NTOK / 4), dim3(256), 0, stream>>>(
        input_ids, time_stamps, ages, W_word, time_w, time_phi, age_w, age_phi, Aws);
    gemm_part_kernel<<<dim3((NTOK / 256) * (HH / 32)), dim3(512), 0, stream>>>(
        type_ids, visit_orders, visit_segments, W_type, W_order, W_seg,
        lin_b, (const short*)Aws, (const short*)Btw, S, Q, out);
    ln_final_kernel<<<dim3(2048), dim3(256), 0, stream>>>(S, Q, ln_g, ln_beta, out);
  } else if (d_ws != nullptr && ws_size >= bt_bytes) {
    short* bt = (short*)d_ws;
    transpose_w_kernel<<<dim3((HH * KK + 255) / 256), dim3(256), 0, stream>>>(lin_W, bt);
    ehr_fallback<true><<<dim3(1024), dim3(512), 0, stream>>>(
        input_ids, type_ids, time_stamps, ages, visit_orders, visit_segments,
        W_word, W_type, W_order, W_seg, time_w, time_phi, age_w, age_phi,
        lin_W, lin_b, ln_g, ln_beta, (const short*)bt, out);
  } else {
    ehr_fallback<false><<<dim3(1024), dim3(512), 0, stream>>>(
        input_ids, type_ids, time_stamps, ages, visit_orders, visit_segments,
        W_word, W_type, W_order, W_seg, time_w, time_phi, age_w, age_phi,
        lin_W, lin_b, ln_g, ln_beta, nullptr, out);
  }
}

// Round 8
// 575.707 us; speedup vs baseline: 1.3934x; 1.0834x over previous
//
#include <hip/hip_runtime.h>
#include <hip/hip_bf16.h>
#include <math.h>
#include <stdint.h>

#define HH 768
#define TT 32
#define KK 832           // H + 2T
#define SS 2048
#define NSTEP 26         // KK / 32
#define NTOK 65536       // B*S

typedef __attribute__((ext_vector_type(4))) float f32x4;
typedef __attribute__((ext_vector_type(8))) short bf16x8;
typedef __attribute__((ext_vector_type(4))) short bf16x4;

__device__ __forceinline__ short f2bf(float f) {
  union { float f; uint32_t u; } v; v.f = f;
  uint32_t u = v.u;
  return (short)((u + 0x7FFFu + ((u >> 16) & 1u)) >> 16);
}

// ---------------- transpose lin_W -> Btw[n][k] bf16 ----------------
__global__ void transpose_w_kernel(const float* __restrict__ lin_W,
                                   short* __restrict__ bt) {
  int i = blockIdx.x * 256 + threadIdx.x;
  if (i >= HH * KK) return;
  int n = i / KK;
  int k = i - n * KK;
  bt[i] = f2bf(lin_W[(size_t)k * HH + n]);
}

// ------------- gather kernel: build A[65536][832] bf16 -------------
__global__ __launch_bounds__(256) void gather_a_kernel(
    const int* __restrict__ input_ids, const float* __restrict__ ts,
    const float* __restrict__ ages, const float* __restrict__ W_word,
    const float* __restrict__ time_w, const float* __restrict__ time_phi,
    const float* __restrict__ age_w, const float* __restrict__ age_phi,
    short* __restrict__ Aws) {
  const int wave = threadIdx.x >> 6, lane = threadIdx.x & 63;
  const int t = blockIdx.x * 4 + wave;
  if (t >= NTOK) return;
  const float* wrow = W_word + (size_t)input_ids[t] * HH;
  const int s = t & (SS - 1);
  const float dt = (s == 0) ? 0.f : (ts[t] - ts[t - 1]);
  const float age = ages[t];
  short* dst = Aws + (size_t)t * KK;
#pragma unroll
  for (int c2 = 0; c2 < 2; ++c2) {
    int chunk = c2 * 64 + lane;
    if (chunk < 104) {
      int k = chunk * 8;
      bf16x8 v;
      if (k < HH) {
        f32x4 x0 = *(const f32x4*)(wrow + k);
        f32x4 x1 = *(const f32x4*)(wrow + k + 4);
        v[0] = f2bf(x0[0]); v[1] = f2bf(x0[1]); v[2] = f2bf(x0[2]); v[3] = f2bf(x0[3]);
        v[4] = f2bf(x1[0]); v[5] = f2bf(x1[1]); v[6] = f2bf(x1[2]); v[7] = f2bf(x1[3]);
      } else if (k < HH + TT) {
        int j = k - HH;
#pragma unroll
        for (int i = 0; i < 8; ++i)
          v[i] = f2bf(sinf(dt * time_w[j + i] + time_phi[j + i]));
      } else {
        int j = k - HH - TT;
#pragma unroll
        for (int i = 0; i < 8; ++i)
          v[i] = f2bf(sinf(age * age_w[j + i] + age_phi[j + i]));
      }
      *(bf16x8*)(dst + k) = v;
    }
  }
}

// ------------- partial-N GEMM: 256 rows x 32 cols per block ---------
// B-slice (32 cols x 832 K = 52KB) staged ONCE into LDS; K-loop is
// barrier-free. Output written with NONTEMPORAL stores (no L2 alloc) so
// streaming writes don't evict the A panels that the 24 sibling n-blocks
// re-read (R7: write pollution caused full A re-fetch, 2.6GB HBM).
__global__ __launch_bounds__(512, 4) void gemm_part_kernel(
    const int* __restrict__ type_ids, const int* __restrict__ visit_orders,
    const int* __restrict__ visit_segments, const float* __restrict__ W_type,
    const float* __restrict__ W_order, const float* __restrict__ W_seg,
    const float* __restrict__ lin_b, const short* __restrict__ Aws,
    const short* __restrict__ Btw, float* __restrict__ S,
    float* __restrict__ Q, float* __restrict__ out) {
  __shared__ short Bl[52 * 512];   // 52KB: chunk c = kc*2+half, [lane][8]
  __shared__ int tyl[256], orl[256], sgl[256];

  // XCD-chunked bijective swizzle: 6144 blocks = 8 XCD x 768.
  const int bid = blockIdx.x;
  const int j = bid >> 3;
  const int mb = (bid & 7) * 32 + j / 24;
  const int nb = j % 24;
  const int m0 = mb * 256, n0 = nb * 32;

  const int tid = threadIdx.x, lane = tid & 63, w = tid >> 6;
  const int l15 = lane & 15, l4 = lane >> 4;

  // ---- stage B slice once (52 x 1KB DMA chunks)
#pragma unroll
  for (int p = 0; p < 7; ++p) {
    int c = p * 8 + w;
    if (c < 52) {
      int kc = c >> 1, half = c & 1;
      const short* src = Btw + (size_t)(n0 + half * 16 + l15) * KK + kc * 32 + l4 * 8;
      __builtin_amdgcn_global_load_lds(
          (const __attribute__((address_space(1))) unsigned int*)src,
          (__attribute__((address_space(3))) unsigned int*)(Bl + c * 512),
          16, 0, 0);
    }
  }
  if (tid < 256) {
    tyl[tid] = type_ids[m0 + tid];
    orl[tid] = visit_orders[m0 + tid];
    sgl[tid] = visit_segments[m0 + tid];
  }
  __syncthreads();   // the ONLY barrier

  // ---- barrier-free K loop
  const short* aptr = Aws + (size_t)(m0 + w * 32 + l15) * KK + l4 * 8;
  f32x4 acc00 = (f32x4)(0.f), acc01 = (f32x4)(0.f);
  f32x4 acc10 = (f32x4)(0.f), acc11 = (f32x4)(0.f);
  const bf16x8* Bf = (const bf16x8*)Bl;

#pragma unroll 4
  for (int st = 0; st < NSTEP; ++st) {
    bf16x8 a0 = *(const bf16x8*)(aptr + st * 32);
    bf16x8 a1 = *(const bf16x8*)(aptr + 16 * KK + st * 32);
    bf16x8 b0 = Bf[(st * 2 + 0) * 64 + lane];
    bf16x8 b1 = Bf[(st * 2 + 1) * 64 + lane];
    acc00 = __builtin_amdgcn_mfma_f32_16x16x32_bf16(a0, b0, acc00, 0, 0, 0);
    acc01 = __builtin_amdgcn_mfma_f32_16x16x32_bf16(a0, b1, acc01, 0, 0, 0);
    acc10 = __builtin_amdgcn_mfma_f32_16x16x32_bf16(a1, b0, acc10, 0, 0, 0);
    acc11 = __builtin_amdgcn_mfma_f32_16x16x32_bf16(a1, b1, acc11, 0, 0, 0);
  }

  // ---- epilogue: tanh + bias + 3 gathers; nontemporal pre-LN stores
  const int nA = n0 + l15, nB = n0 + 16 + l15;
  const float biasA = lin_b[nA], biasB = lin_b[nB];
  float sp[2][4], sq[2][4];
#pragma unroll
  for (int mf = 0; mf < 2; ++mf)
#pragma unroll
    for (int r = 0; r < 4; ++r) { sp[mf][r] = 0.f; sq[mf][r] = 0.f; }

#pragma unroll
  for (int mf = 0; mf < 2; ++mf) {
#pragma unroll
    for (int r = 0; r < 4; ++r) {
      int row_l = w * 32 + mf * 16 + l4 * 4 + r;
      size_t ty = (size_t)tyl[row_l] * HH;
      size_t od = (size_t)orl[row_l] * HH;
      size_t sg = (size_t)sgl[row_l] * HH;
      float zA = tanhf((mf ? acc10[r] : acc00[r]) + biasA)
                 + W_type[ty + nA] + W_order[od + nA] + W_seg[sg + nA];
      float zB = tanhf((mf ? acc11[r] : acc01[r]) + biasB)
                 + W_type[ty + nB] + W_order[od + nB] + W_seg[sg + nB];
      float* op = out + (size_t)(m0 + row_l) * HH;
      __builtin_nontemporal_store(zA, op + nA);
      __builtin_nontemporal_store(zB, op + nB);
      sp[mf][r] += zA + zB;
      sq[mf][r] += zA * zA + zB * zB;
    }
  }
#pragma unroll
  for (int m = 1; m < 16; m <<= 1) {
#pragma unroll
    for (int mf = 0; mf < 2; ++mf)
#pragma unroll
      for (int r = 0; r < 4; ++r) {
        sp[mf][r] += __shfl_xor(sp[mf][r], m, 64);
        sq[mf][r] += __shfl_xor(sq[mf][r], m, 64);
      }
  }
  if (l15 == 0) {
#pragma unroll
    for (int mf = 0; mf < 2; ++mf)
#pragma unroll
      for (int r = 0; r < 4; ++r) {
        int row_g = m0 + w * 32 + mf * 16 + l4 * 4 + r;
        atomicAdd(&S[row_g], sp[mf][r]);
        atomicAdd(&Q[row_g], sq[mf][r]);
      }
  }
}

// ------------- final LayerNorm pass: in-place on out ----------------
__global__ __launch_bounds__(256) void ln_final_kernel(
    const float* __restrict__ S, const float* __restrict__ Q,
    const float* __restrict__ ln_g, const float* __restrict__ ln_beta,
    float* __restrict__ out) {
  const int lane = threadIdx.x & 63, w = threadIdx.x >> 6;
  const int c0 = lane * 4;
  const f32x4 g0 = *(const f32x4*)(ln_g + c0);
  const f32x4 g1 = *(const f32x4*)(ln_g + 256 + c0);
  const f32x4 g2 = *(const f32x4*)(ln_g + 512 + c0);
  const f32x4 e0 = *(const f32x4*)(ln_beta + c0);
  const f32x4 e1 = *(const f32x4*)(ln_beta + 256 + c0);
  const f32x4 e2 = *(const f32x4*)(ln_beta + 512 + c0);
  const int wid = blockIdx.x * 4 + w;   // 0..8191
#pragma unroll 1
  for (int i = 0; i < 8; ++i) {
    int row = wid + i * 8192;
    float* rp = out + (size_t)row * HH;
    f32x4 x0 = *(const f32x4*)(rp + c0);
    f32x4 x1 = *(const f32x4*)(rp + 256 + c0);
    f32x4 x2 = *(const f32x4*)(rp + 512 + c0);
    float s = S[row], q = Q[row];
    float mu = s * (1.0f / 768.0f);
    float var = q * (1.0f / 768.0f) - mu * mu;
    if (var < 0.f) var = 0.f;
    float rs = rsqrtf(var + 1e-12f);
    f32x4 y0, y1, y2;
#pragma unroll
    for (int k = 0; k < 4; ++k) {
      y0[k] = (x0[k] - mu) * rs * g0[k] + e0[k];
      y1[k] = (x1[k] - mu) * rs * g1[k] + e1[k];
      y2[k] = (x2[k] - mu) * rs * g2[k] + e2[k];
    }
    __builtin_nontemporal_store(y0, (f32x4*)(rp + c0));
    __builtin_nontemporal_store(y1, (f32x4*)(rp + 256 + c0));
    __builtin_nontemporal_store(y2, (f32x4*)(rp + 512 + c0));
  }
}

// =================== fallback (R1 kernel, ws-light) ===================
template <bool WS>
__global__ __launch_bounds__(512, 1) void ehr_fallback(
    const int* __restrict__ input_ids, const int* __restrict__ type_ids,
    const float* __restrict__ time_stamps, const float* __restrict__ ages,
    const int* __restrict__ visit_orders, const int* __restrict__ visit_segments,
    const float* __restrict__ W_word, const float* __restrict__ W_type,
    const float* __restrict__ W_order, const float* __restrict__ W_seg,
    const float* __restrict__ time_w, const float* __restrict__ time_phi,
    const float* __restrict__ age_w, const float* __restrict__ age_phi,
    const float* __restrict__ lin_W, const float* __restrict__ lin_b,
    const float* __restrict__ ln_g, const float* __restrict__ ln_beta,
    const short* __restrict__ bt_ws, float* __restrict__ out) {
  __shared__ short Bt[HH * 32];
  __shared__ short Atile[64 * 32];
  __shared__ float dtl[64], agel[64];
  __shared__ int idl[64], tyl[64], orl[64], sgl[64];
  __shared__ float tpar[128];
  __shared__ float redS[4][64], redQ[4][64];

  const int tid = threadIdx.x;
  const int t0 = blockIdx.x * 64;

  if (tid < 128) {
    int j = tid & 31;
    float v;
    if (tid < 32) v = time_w[j];
    else if (tid < 64) v = time_phi[j];
    else if (tid < 96) v = age_w[j];
    else v = age_phi[j];
    tpar[tid] = v;
  }
  if (tid < 64) {
    int t = t0 + tid;
    int s = t & (SS - 1);
    float tsv = time_stamps[t];
    dtl[tid] = (s == 0) ? 0.f : (tsv - time_stamps[t - 1]);
    agel[tid] = ages[t];
    idl[tid] = input_ids[t];
    tyl[tid] = type_ids[t];
    orl[tid] = visit_orders[t];
    sgl[tid] = visit_segments[t];
  }
  __syncthreads();

  const int lane = tid & 63, wave = tid >> 6;
  const int wm = wave >> 2, wn = wave & 3;
  const int l15 = lane & 15, l4 = lane >> 4;
  const int arow = tid >> 3, ac = tid & 7;
  const int myid = idl[arow];
  const float mydt = dtl[arow];
  const float myage = agel[arow];
  const float* wrow = W_word + (size_t)myid * HH;

  f32x4 acc[2][12];
#pragma unroll
  for (int mf = 0; mf < 2; ++mf)
#pragma unroll
    for (int nf = 0; nf < 12; ++nf) acc[mf][nf] = (f32x4)(0.0f);

  for (int st = 0; st < NSTEP; ++st) {
    const int k0 = st * 32;
    {
      int kg = k0 + ac * 4;
      bf16x4 w4;
      if (kg < HH) {
        const f32x4 v = *(const f32x4*)(wrow + kg);
        w4[0] = f2bf(v[0]); w4[1] = f2bf(v[1]);
        w4[2] = f2bf(v[2]); w4[3] = f2bf(v[3]);
      } else {
        int isAge = (kg >= HH + TT);
        int j = kg - (isAge ? (HH + TT) : HH);
        float x = isAge ? myage : mydt;
        int wof = isAge ? 64 : 0;
#pragma unroll
        for (int i = 0; i < 4; ++i)
          w4[i] = f2bf(sinf(x * tpar[wof + j + i] + tpar[wof + 32 + j + i]));
      }
      *(bf16x4*)(Atile + tid * 4) = w4;
    }
    if (WS) {
#pragma unroll
      for (int p = 0; p < 6; ++p) {
        int chunk = p * 8 + wave;
        short* ldst = Bt + chunk * 512;
        int n = chunk * 16 + (lane >> 2);
        int q = lane & 3;
        const short* src = bt_ws + (size_t)n * KK + k0 + q * 8;
        __builtin_amdgcn_global_load_lds(
            (const __attribute__((address_space(1))) unsigned int*)src,
            (__attribute__((address_space(3))) unsigned int*)ldst, 16, 0, 0);
      }
    } else {
#pragma unroll
      for (int i6 = 0; i6 < 6; ++i6) {
        int c = i6 * 512 + tid;
        int n = c >> 2, q = c & 3;
        int kb = k0 + q * 8;
        bf16x8 w8;
#pragma unroll
        for (int j = 0; j < 8; ++j) w8[j] = f2bf(lin_W[(size_t)(kb + j) * HH + n]);
        *(bf16x8*)(Bt + n * 32 + q * 8) = w8;
      }
    }
    __syncthreads();

    const bf16x8* Af = (const bf16x8*)Atile;
    const bf16x8* Bf = (const bf16x8*)Bt;
    bf16x8 a0 = Af[(wm * 32 + l15) * 4 + l4];
    bf16x8 a1 = Af[(wm * 32 + 16 + l15) * 4 + l4];
#pragma unroll
    for (int nf = 0; nf < 12; ++nf) {
      int n = wn * 192 + nf * 16 + l15;
      bf16x8 b = Bf[n * 4 + l4];
      acc[0][nf] = __builtin_amdgcn_mfma_f32_16x16x32_bf16(a0, b, acc[0][nf], 0, 0, 0);
      acc[1][nf] = __builtin_amdgcn_mfma_f32_16x16x32_bf16(a1, b, acc[1][nf], 0, 0, 0);
    }
    __syncthreads();
  }

  float sp[2][4], sq[2][4];
#pragma unroll
  for (int mf = 0; mf < 2; ++mf)
#pragma unroll
    for (int r = 0; r < 4; ++r) { sp[mf][r] = 0.f; sq[mf][r] = 0.f; }

#pragma unroll
  for (int nf = 0; nf < 12; ++nf) {
    int n = wn * 192 + nf * 16 + l15;
    float bias = lin_b[n];
#pragma unroll
    for (int mf = 0; mf < 2; ++mf) {
#pragma unroll
      for (int r = 0; r < 4; ++r) {
        int row = wm * 32 + mf * 16 + l4 * 4 + r;
        float z = tanhf(acc[mf][nf][r] + bias);
        z += W_type[(size_t)tyl[row] * HH + n];
        z += W_order[(size_t)orl[row] * HH + n];
        z += W_seg[(size_t)sgl[row] * HH + n];
        acc[mf][nf][r] = z;
        sp[mf][r] += z;
        sq[mf][r] += z * z;
      }
    }
  }
#pragma unroll
  for (int m = 1; m < 16; m <<= 1) {
#pragma unroll
    for (int mf = 0; mf < 2; ++mf)
#pragma unroll
      for (int r = 0; r < 4; ++r) {
        sp[mf][r] += __shfl_xor(sp[mf][r], m, 64);
        sq[mf][r] += __shfl_xor(sq[mf][r], m, 64);
      }
  }
  if (l15 == 0) {
#pragma unroll
    for (int mf = 0; mf < 2; ++mf)
#pragma unroll
      for (int r = 0; r < 4; ++r) {
        int row = wm * 32 + mf * 16 + l4 * 4 + r;
        redS[wn][row] = sp[mf][r];
        redQ[wn][row] = sq[mf][r];
      }
  }
  __syncthreads();

  float mu[2][4], rs[2][4];
#pragma unroll
  for (int mf = 0; mf < 2; ++mf)
#pragma unroll
    for (int r = 0; r < 4; ++r) {
      int row = wm * 32 + mf * 16 + l4 * 4 + r;
      float s = redS[0][row] + redS[1][row] + redS[2][row] + redS[3][row];
      float q = redQ[0][row] + redQ[1][row] + redQ[2][row] + redQ[3][row];
      float m_ = s * (1.0f / 768.0f);
      float v_ = q * (1.0f / 768.0f) - m_ * m_;
      if (v_ < 0.f) v_ = 0.f;
      mu[mf][r] = m_;
      rs[mf][r] = rsqrtf(v_ + 1e-12f);
    }

#pragma unroll
  for (int nf = 0; nf < 12; ++nf) {
    int n = wn * 192 + nf * 16 + l15;
    float g = ln_g[n], be = ln_beta[n];
#pragma unroll
    for (int mf = 0; mf < 2; ++mf) {
#pragma unroll
      for (int r = 0; r < 4; ++r) {
        int row = wm * 32 + mf * 16 + l4 * 4 + r;
        out[(size_t)(t0 + row) * HH + n] =
            (acc[mf][nf][r] - mu[mf][r]) * rs[mf][r] * g + be;
      }
    }
  }
}

extern "C" void kernel_launch(void* const* d_in, const int* in_sizes, int n_in,
                              void* d_out, int out_size, void* d_ws, size_t ws_size,
                              hipStream_t stream) {
  const int* input_ids = (const int*)d_in[0];
  const int* type_ids = (const int*)d_in[1];
  const float* time_stamps = (const float*)d_in[2];
  const float* ages = (const float*)d_in[3];
  const int* visit_orders = (const int*)d_in[4];
  const int* visit_segments = (const int*)d_in[5];
  const float* W_word = (const float*)d_in[6];
  const float* W_type = (const float*)d_in[7];
  const float* W_order = (const float*)d_in[8];
  const float* W_seg = (const float*)d_in[9];
  const float* time_w = (const float*)d_in[10];
  const float* time_phi = (const float*)d_in[11];
  const float* age_w = (const float*)d_in[12];
  const float* age_phi = (const float*)d_in[13];
  const float* lin_W = (const float*)d_in[14];
  const float* lin_b = (const float*)d_in[15];
  const float* ln_g = (const float*)d_in[16];
  const float* ln_beta = (const float*)d_in[17];
  float* out = (float*)d_out;

  const size_t a_bytes = (size_t)NTOK * KK * sizeof(short);   // ~109 MB
  const size_t bt_bytes = (size_t)HH * KK * sizeof(short);    // ~1.3 MB
  const size_t st_bytes = (size_t)NTOK * sizeof(float);       // 256 KB each

  if (d_ws != nullptr && ws_size >= a_bytes + bt_bytes + 2 * st_bytes) {
    short* Aws = (short*)d_ws;
    short* Btw = (short*)((char*)d_ws + a_bytes);
    float* S = (float*)((char*)d_ws + a_bytes + bt_bytes);
    float* Q = S + NTOK;
    hipMemsetAsync(S, 0, 2 * st_bytes, stream);
    transpose_w_kernel<<<dim3((HH * KK + 255) / 256), dim3(256), 0, stream>>>(lin_W, Btw);
    gather_a_kernel<<<dim3(NTOK / 4), dim3(256), 0, stream>>>(
        input_ids, time_stamps, ages, W_word, time_w, time_phi, age_w, age_phi, Aws);
    gemm_part_kernel<<<dim3((NTOK / 256) * (HH / 32)), dim3(512), 0, stream>>>(
        type_ids, visit_orders, visit_segments, W_type, W_order, W_seg,
        lin_b, (const short*)Aws, (const short*)Btw, S, Q, out);
    ln_final_kernel<<<dim3(2048), dim3(256), 0, stream>>>(S, Q, ln_g, ln_beta, out);
  } else if (d_ws != nullptr && ws_size >= bt_bytes) {
    short* bt = (short*)d_ws;
    transpose_w_kernel<<<dim3((HH * KK + 255) / 256), dim3(256), 0, stream>>>(lin_W, bt);
    ehr_fallback<true><<<dim3(1024), dim3(512), 0, stream>>>(
        input_ids, type_ids, time_stamps, ages, visit_orders, visit_segments,
        W_word, W_type, W_order, W_seg, time_w, time_phi, age_w, age_phi,
        lin_W, lin_b, ln_g, ln_beta, (const short*)bt, out);
  } else {
    ehr_fallback<false><<<dim3(1024), dim3(512), 0, stream>>>(
        input_ids, type_ids, time_stamps, ages, visit_orders, visit_segments,
        W_word, W_type, W_order, W_seg, time_w, time_phi, age_w, age_phi,
        lin_W, lin_b, ln_g, ln_beta, nullptr, out);
  }
}